// Round 1
// 2074.518 us; speedup vs baseline: 1.0563x; 1.0563x over previous
//
#include <hip/hip_runtime.h>

#define NTOT 65536

typedef __attribute__((ext_vector_type(8))) short bf16x8;   // 8 bf16 (4 VGPRs)
typedef __attribute__((ext_vector_type(4))) float f32x4;

__device__ __forceinline__ float bf2f(unsigned short u) {
    union { unsigned int i; float f; } v; v.i = ((unsigned int)u) << 16; return v.f;
}
__device__ __forceinline__ unsigned short f2bf(float f) {
    union { float f; unsigned int i; } v; v.f = f;
    unsigned int i = v.i;
    return (unsigned short)((i + 0x7FFFu + ((i >> 16) & 1u)) >> 16);  // RNE
}
__device__ __forceinline__ float lo16(unsigned int v) { return bf2f((unsigned short)(v & 0xFFFFu)); }
__device__ __forceinline__ float hi16(unsigned int v) { return bf2f((unsigned short)(v >> 16)); }

// async global->LDS, 16B/lane; LDS dest is wave-uniform base + lane*16 by construction
__device__ __forceinline__ void gload16(const void* g, void* l) {
    __builtin_amdgcn_global_load_lds((const __attribute__((address_space(1))) void*)(g),
                                     (__attribute__((address_space(3))) void*)(l), 16, 0, 0);
}

// ---------------- fp32 -> bf16 bulk converter (8 elems/thread) ----------------
__global__ __launch_bounds__(256) void cvt_bf16(const float* __restrict__ src,
                                                unsigned short* __restrict__ dst) {
    size_t i = ((size_t)blockIdx.x * 256 + threadIdx.x) * 8;
    float4 a = *(const float4*)(src + i);
    float4 b = *(const float4*)(src + i + 4);
    unsigned int o0 = (unsigned int)f2bf(a.x) | ((unsigned int)f2bf(a.y) << 16);
    unsigned int o1 = (unsigned int)f2bf(a.z) | ((unsigned int)f2bf(a.w) << 16);
    unsigned int o2 = (unsigned int)f2bf(b.x) | ((unsigned int)f2bf(b.y) << 16);
    unsigned int o3 = (unsigned int)f2bf(b.z) | ((unsigned int)f2bf(b.w) << 16);
    uint4 o = {o0, o1, o2, o3};
    *(uint4*)(dst + i) = o;
}

// ---------------- zero counters ----------------
__global__ void zero_counts(int* c1, int* c2) {
    if (threadIdx.x < 16) { c1[threadIdx.x] = 0; c2[threadIdx.x] = 0; }
}

// ---------------- M = U @ Pw, fp64: [3*12, 1024] ----------------
// z = (x@Pw^T)@U^T == x@(U@Pw)^T exactly in real arithmetic; fp64 accumulation of
// either association is ~exact, so routing decisions match the previous fp64 path.
__global__ __launch_bounds__(256) void compute_M(const float* __restrict__ U1,
                                                 const float* __restrict__ U2,
                                                 const float* __restrict__ U3,
                                                 const float* __restrict__ Pw,
                                                 double* __restrict__ M) {
    int le = blockIdx.x;              // 0..35
    int l = le / 12, e = le % 12;
    const float* U = (l == 0 ? U1 : (l == 1 ? U2 : U3)) + e * 64;
    int c = threadIdx.x * 4;
    double a0 = 0.0, a1 = 0.0, a2 = 0.0, a3 = 0.0;
    for (int a = 0; a < 64; a++) {
        double u = (double)U[a];                      // wave-uniform -> scalar load
        float4 p = *(const float4*)&Pw[(size_t)a * 1024 + c];
        a0 += u * (double)p.x; a1 += u * (double)p.y;
        a2 += u * (double)p.z; a3 += u * (double)p.w;
    }
    double* mp = M + (size_t)le * 1024 + c;
    mp[0] = a0; mp[1] = a1; mp[2] = a2; mp[3] = a3;
}

// ---------------- z[n][36] = x[n] @ M^T, fp64 accum ----------------
// block = 128 tokens, 256 threads; thread = 2 tokens x 9 experts.
// X tile staged via global_load_lds with XOR-swizzled SOURCE (linear LDS dest),
// read back with the matching swizzle -> conflict-free ds_read_b128.
// M chunk staged fp64 in LDS; reads are wave-uniform broadcasts (no conflict).
__global__ __launch_bounds__(256) void z_gemm(const float* __restrict__ X,
                                              const double* __restrict__ Mg,
                                              double* __restrict__ z, int tok_base) {
    __shared__ __align__(16) float xs[128 * 64];     // 32 KB
    __shared__ __align__(16) double Ms[36 * 64];     // 18 KB
    const int tid = threadIdx.x;
    const int w = tid >> 6, lane = tid & 63;
    const int tok0 = tid & 63, tok1 = tok0 + 64;
    const int eg = tid >> 6;                          // expert group: eg*9 .. eg*9+8
    const int tb = blockIdx.x * 128;

    double acc[2][9];
#pragma unroll
    for (int t = 0; t < 2; t++)
#pragma unroll
        for (int j = 0; j < 9; j++) acc[t][j] = 0.0;

    for (int kc = 0; kc < 16; ++kc) {
        int k0 = kc * 64;
        // stage: 32 X-instrs (1KB each) + 18 M-instrs, round-robined over 4 waves
        for (int i = w; i < 50; i += 4) {
            if (i < 32) {
                int r = i * 4 + (lane >> 4);          // row 0..127
                int p = lane & 15;                    // physical 16B chunk
                const float* g = X + (size_t)(tok_base + tb + r) * 1024 + k0 + ((p ^ (r & 7)) << 2);
                gload16(g, xs + i * 256 + lane * 4);
            } else {
                int ii = i - 32;                      // 0..17
                int e = ii * 2 + (lane >> 5);         // 0..35
                const double* g = Mg + (size_t)e * 1024 + k0 + ((lane & 31) << 1);
                gload16(g, Ms + ii * 128 + lane * 2);
            }
        }
        __syncthreads();
#pragma unroll
        for (int kq = 0; kq < 16; ++kq) {
            int p = (kq ^ (tok0 & 7)) << 2;           // swizzled float offset
            float4 xa4 = *(const float4*)&xs[(tok0 << 6) + p];
            float4 xb4 = *(const float4*)&xs[(tok1 << 6) + p];
            double xd00 = (double)xa4.x, xd01 = (double)xa4.y,
                   xd02 = (double)xa4.z, xd03 = (double)xa4.w;
            double xd10 = (double)xb4.x, xd11 = (double)xb4.y,
                   xd12 = (double)xb4.z, xd13 = (double)xb4.w;
            const double* mp = &Ms[(eg * 9) * 64 + (kq << 2)];
#pragma unroll
            for (int j = 0; j < 9; j++) {
                double2 m0 = *(const double2*)(mp + j * 64);
                double2 m1 = *(const double2*)(mp + j * 64 + 2);
                acc[0][j] += xd00 * m0.x + xd01 * m0.y + xd02 * m1.x + xd03 * m1.y;
                acc[1][j] += xd10 * m0.x + xd11 * m0.y + xd12 * m1.x + xd13 * m1.y;
            }
        }
        __syncthreads();
    }
    double* zp0 = z + (size_t)(tb + tok0) * 36 + eg * 9;
    double* zp1 = z + (size_t)(tb + tok1) * 36 + eg * 9;
#pragma unroll
    for (int j = 0; j < 9; j++) { zp0[j] = acc[0][j]; zp1[j] = acc[1][j]; }
}

// ---------------- routing: read z[36] fp64, top-3, softmax, bucket build ----------------
__global__ __launch_bounds__(256) void route2(
    const double* __restrict__ z,
    int* __restrict__ counts1, int* __restrict__ counts2,
    int* __restrict__ bucket1, float* __restrict__ bucketw1,
    int* __restrict__ bucket2, float* __restrict__ bucketw2,
    int* __restrict__ topi3, float* __restrict__ topw3, int Nc) {
    __shared__ int lcnt1[12], lcnt2[12], gbase1[12], gbase2[12];
    int tid = threadIdx.x;
    if (tid < 12) { lcnt1[tid] = 0; lcnt2[tid] = 0; }
    __syncthreads();
    int n = blockIdx.x * 256 + tid;
    int ei[3][3]; float ew[3][3];
    for (int l = 0; l < 3; l++) {
        double zz[12];
        const double* zp = z + (size_t)n * 36 + l * 12;
#pragma unroll
        for (int e = 0; e < 12; e += 2) {
            double2 v = *(const double2*)(zp + e);
            zz[e] = v.x; zz[e + 1] = v.y;
        }
        int i0 = 0, i1 = 0, i2 = 0; double v0 = -1e300, v1 = -1e300, v2 = -1e300;
#pragma unroll
        for (int e = 0; e < 12; e++) {
            double v = zz[e];
            if (v > v0)      { v2 = v1; i2 = i1; v1 = v0; i1 = i0; v0 = v; i0 = e; }
            else if (v > v1) { v2 = v1; i2 = i1; v1 = v; i1 = e; }
            else if (v > v2) { v2 = v; i2 = e; }
        }
        float inv = 1.0f / (1.0f + 1e-8f);
        float e1 = expf((float)(v1 - v0) * inv), e2 = expf((float)(v2 - v0) * inv);
        float s = 1.0f + e1 + e2;
        ew[l][0] = 1.0f / s; ew[l][1] = e1 / s; ew[l][2] = e2 / s;
        ei[l][0] = i0; ei[l][1] = i1; ei[l][2] = i2;
    }
    int lpos1[3], lpos2[3];
    for (int s = 0; s < 3; s++) {
        lpos1[s] = atomicAdd(&lcnt1[ei[0][s]], 1);
        lpos2[s] = atomicAdd(&lcnt2[ei[1][s]], 1);
    }
    __syncthreads();
    if (tid < 12) {
        gbase1[tid] = atomicAdd(&counts1[tid], lcnt1[tid]);
        gbase2[tid] = atomicAdd(&counts2[tid], lcnt2[tid]);
    }
    __syncthreads();
    for (int s = 0; s < 3; s++) {
        int e = ei[0][s]; int pos = gbase1[e] + lpos1[s];
        bucket1[e * Nc + pos] = (s << 16) | n;
        bucketw1[e * Nc + pos] = ew[0][s];
        e = ei[1][s]; pos = gbase2[e] + lpos2[s];
        bucket2[e * Nc + pos] = (s << 16) | n;
        bucketw2[e * Nc + pos] = ew[1][s];
        topi3[n * 3 + s] = ei[2][s];
        topw3[n * 3 + s] = ew[2][s];
    }
}

// ---------------- grouped GEMM: per-expert gathered rows, weight-scaled scatter to part ----------------
__global__ __launch_bounds__(256) void grouped_gemm(
    const unsigned short* __restrict__ A,       // [Nc,1024] bf16 (chunk-local rows)
    const unsigned short* __restrict__ W,       // [12,1024,1024] bf16, B^T form
    const int* __restrict__ bucket, const float* __restrict__ bucketw,
    const int* __restrict__ counts,
    unsigned short* __restrict__ part, int Nc) { // [3][Nc][1024] bf16
    __shared__ unsigned short As[128 * 32];
    __shared__ unsigned short Bs[128 * 32];
    __shared__ int ids[128];
    __shared__ float wts[128];
    int bx = blockIdx.x;
    int e = -1, mt = 0, accum = 0, Me = 0;
    for (int ee = 0; ee < 12; ee++) {
        int c = counts[ee];
        int t = (c + 127) >> 7;
        if (e < 0 && bx < accum + t) { e = ee; mt = bx - accum; Me = c; }
        accum += t;
    }
    if (e < 0) return;
    int nt = blockIdx.y;
    int tid = threadIdx.x, lane = tid & 63, w = tid >> 6;
    int m0 = mt << 7;
    if (tid < 128) {
        int r = m0 + tid; if (r >= Me) r = Me - 1;
        ids[tid] = bucket[e * Nc + r];
        wts[tid] = bucketw[e * Nc + r];
    }
    __syncthreads();
    int seg = lane & 3;
    int rA0 = w * 16 + (lane >> 2);
    int rA1 = rA0 + 64;
    const unsigned short* a0p = A + (size_t)(ids[rA0] & 0xFFFF) * 1024 + seg * 8;
    const unsigned short* a1p = A + (size_t)(ids[rA1] & 0xFFFF) * 1024 + seg * 8;
    const unsigned short* b0p = W + (size_t)e * 1048576 + (size_t)(nt * 128 + rA0) * 1024 + seg * 8;
    const unsigned short* b1p = W + (size_t)e * 1048576 + (size_t)(nt * 128 + rA1) * 1024 + seg * 8;
    unsigned short* AsL0 = &As[w * 512 + lane * 8];
    unsigned short* AsL1 = &As[(w + 4) * 512 + lane * 8];
    unsigned short* BsL0 = &Bs[w * 512 + lane * 8];
    unsigned short* BsL1 = &Bs[(w + 4) * 512 + lane * 8];
    f32x4 acc[4][4];
    for (int i = 0; i < 4; i++) for (int j = 0; j < 4; j++) acc[i][j] = (f32x4){0.f, 0.f, 0.f, 0.f};
    int wr0 = (w & 1) * 64, wc0 = (w >> 1) * 64;
    for (int it = 0; it < 32; ++it) {
        int k0 = it * 32;
        gload16(a0p + k0, AsL0);
        gload16(a1p + k0, AsL1);
        gload16(b0p + k0, BsL0);
        gload16(b1p + k0, BsL1);
        __syncthreads();
        int q = lane >> 4, l15 = lane & 15;
        bf16x8 af[4], bfr[4];
        for (int i = 0; i < 4; i++) af[i]  = *(const bf16x8*)&As[(wr0 + i * 16 + l15) * 32 + q * 8];
        for (int j = 0; j < 4; j++) bfr[j] = *(const bf16x8*)&Bs[(wc0 + j * 16 + l15) * 32 + q * 8];
        for (int i = 0; i < 4; i++)
            for (int j = 0; j < 4; j++)
                acc[i][j] = __builtin_amdgcn_mfma_f32_16x16x32_bf16(af[i], bfr[j], acc[i][j], 0, 0, 0);
        __syncthreads();
    }
    int q = lane >> 4, l15 = lane & 15;
    for (int i = 0; i < 4; i++) {
        for (int r = 0; r < 4; r++) {
            int row = wr0 + i * 16 + q * 4 + r;
            if (m0 + row >= Me) continue;
            int id = ids[row];
            int n = id & 0xFFFF, slot = id >> 16;
            float wt = wts[row];
            size_t base = ((size_t)slot * Nc + n) * 1024 + (size_t)(nt * 128 + wc0);
            for (int j = 0; j < 4; j++)
                part[base + j * 16 + l15] = f2bf(acc[i][j][r] * wt);
        }
    }
}

// ---------------- h = gelu(sum_slots part), bf16 out ----------------
__global__ __launch_bounds__(256) void combine_gelu(const unsigned short* __restrict__ part,
                                                    unsigned short* __restrict__ h, int Nc) {
    size_t idx = ((size_t)blockIdx.x * 256 + threadIdx.x) * 8;
    const size_t S = (size_t)Nc * 1024;
    uint4 a = *(const uint4*)(part + idx);
    uint4 b = *(const uint4*)(part + S + idx);
    uint4 c = *(const uint4*)(part + 2 * S + idx);
    unsigned int pa[4] = {a.x, a.y, a.z, a.w};
    unsigned int pb[4] = {b.x, b.y, b.z, b.w};
    unsigned int pc[4] = {c.x, c.y, c.z, c.w};
    unsigned int po[4];
    for (int k = 0; k < 4; k++) {
        float s0 = lo16(pa[k]) + lo16(pb[k]) + lo16(pc[k]);
        float s1 = hi16(pa[k]) + hi16(pb[k]) + hi16(pc[k]);
        float g0 = 0.5f * s0 * (1.0f + erff(s0 * 0.70710678118654752f));
        float g1 = 0.5f * s1 * (1.0f + erff(s1 * 0.70710678118654752f));
        po[k] = (unsigned int)f2bf(g0) | ((unsigned int)f2bf(g1) << 16);
    }
    uint4 o = {po[0], po[1], po[2], po[3]};
    *(uint4*)(h + idx) = o;
}

// ---------------- out(fp32) = sum_slots part + C3 @ b2(fp32) ----------------
__global__ __launch_bounds__(256) void final_out(const unsigned short* __restrict__ part,
                                                 const int* __restrict__ topi3,
                                                 const float* __restrict__ topw3,
                                                 const float* __restrict__ b2,
                                                 float* __restrict__ out, int Nc) {
    size_t idx = ((size_t)blockIdx.x * 256 + threadIdx.x) * 8;
    const size_t S = (size_t)Nc * 1024;
    int n = (int)(idx >> 10), col = (int)(idx & 1023);
    uint4 a = *(const uint4*)(part + idx);
    uint4 b = *(const uint4*)(part + S + idx);
    uint4 c = *(const uint4*)(part + 2 * S + idx);
    int e0 = topi3[n * 3 + 0], e1 = topi3[n * 3 + 1], e2 = topi3[n * 3 + 2];
    float w0 = topw3[n * 3 + 0], w1 = topw3[n * 3 + 1], w2 = topw3[n * 3 + 2];
    unsigned int pa[4] = {a.x, a.y, a.z, a.w};
    unsigned int pb[4] = {b.x, b.y, b.z, b.w};
    unsigned int pc[4] = {c.x, c.y, c.z, c.w};
    float r[8];
    for (int k = 0; k < 4; k++) {
        r[2 * k]     = lo16(pa[k]) + lo16(pb[k]) + lo16(pc[k]);
        r[2 * k + 1] = hi16(pa[k]) + hi16(pb[k]) + hi16(pc[k]);
    }
    const float* q0 = b2 + (size_t)e0 * 1024 + col;
    const float* q1 = b2 + (size_t)e1 * 1024 + col;
    const float* q2 = b2 + (size_t)e2 * 1024 + col;
    float4 q0a = *(const float4*)q0, q0b = *(const float4*)(q0 + 4);
    float4 q1a = *(const float4*)q1, q1b = *(const float4*)(q1 + 4);
    float4 q2a = *(const float4*)q2, q2b = *(const float4*)(q2 + 4);
    float bz[8] = {q0a.x * w0 + q1a.x * w1 + q2a.x * w2, q0a.y * w0 + q1a.y * w1 + q2a.y * w2,
                   q0a.z * w0 + q1a.z * w1 + q2a.z * w2, q0a.w * w0 + q1a.w * w1 + q2a.w * w2,
                   q0b.x * w0 + q1b.x * w1 + q2b.x * w2, q0b.y * w0 + q1b.y * w1 + q2b.y * w2,
                   q0b.z * w0 + q1b.z * w1 + q2b.z * w2, q0b.w * w0 + q1b.w * w1 + q2b.w * w2};
    float4 o0 = {r[0] + bz[0], r[1] + bz[1], r[2] + bz[2], r[3] + bz[3]};
    float4 o1 = {r[4] + bz[4], r[5] + bz[5], r[6] + bz[6], r[7] + bz[7]};
    *(float4*)(out + idx) = o0;
    *(float4*)(out + idx + 4) = o1;
}

// ---------------- host: adaptive chunking so ws fits ----------------
struct WsPlan {
    size_t w1b, w2b, xb, m, z, c1, c2, bk1, bw1, bk2, bw2, ti, tw, h, part, total;
};
static WsPlan plan_ws(size_t Nc) {
    auto al = [](size_t x) { return (x + 255) & ~(size_t)255; };
    WsPlan p; size_t o = 0;
    p.w1b = o; o = al(o + (size_t)12 * 1024 * 1024 * 2);
    p.w2b = o; o = al(o + (size_t)12 * 1024 * 1024 * 2);
    p.xb  = o; o = al(o + Nc * 1024 * 2);
    p.m   = o; o = al(o + (size_t)36 * 1024 * 8);
    p.z   = o; o = al(o + Nc * 36 * 8);
    p.c1  = o; o = al(o + 64);
    p.c2  = o; o = al(o + 64);
    p.bk1 = o; o = al(o + 12 * Nc * 4);
    p.bw1 = o; o = al(o + 12 * Nc * 4);
    p.bk2 = o; o = al(o + 12 * Nc * 4);
    p.bw2 = o; o = al(o + 12 * Nc * 4);
    p.ti  = o; o = al(o + Nc * 3 * 4);
    p.tw  = o; o = al(o + Nc * 3 * 4);
    p.h   = o; o = al(o + Nc * 1024 * 2);
    p.part= o; o = al(o + (size_t)3 * Nc * 1024 * 2);
    p.total = o;
    return p;
}

extern "C" void kernel_launch(void* const* d_in, const int* in_sizes, int n_in,
                              void* d_out, int out_size, void* d_ws, size_t ws_size,
                              hipStream_t stream) {
    const float* X  = (const float*)d_in[0];
    const float* Pw = (const float*)d_in[1];
    const float* U1 = (const float*)d_in[2];
    const float* U2 = (const float*)d_in[3];
    const float* U3 = (const float*)d_in[4];
    const float* W1 = (const float*)d_in[5];
    const float* W2 = (const float*)d_in[6];
    const float* B2 = (const float*)d_in[7];
    float* OUT = (float*)d_out;

    int C = 1;
    while (C < 64 && plan_ws(NTOT / C).total > ws_size) C <<= 1;
    int Nc = NTOT / C;
    WsPlan p = plan_ws((size_t)Nc);

    char* ws = (char*)d_ws;
    unsigned short* W1b  = (unsigned short*)(ws + p.w1b);
    unsigned short* W2b  = (unsigned short*)(ws + p.w2b);
    unsigned short* Xb   = (unsigned short*)(ws + p.xb);
    double* Md      = (double*)(ws + p.m);
    double* zbuf    = (double*)(ws + p.z);
    int* counts1    = (int*)(ws + p.c1);
    int* counts2    = (int*)(ws + p.c2);
    int* bucket1    = (int*)(ws + p.bk1);
    float* bucketw1 = (float*)(ws + p.bw1);
    int* bucket2    = (int*)(ws + p.bk2);
    float* bucketw2 = (float*)(ws + p.bw2);
    int* topi3      = (int*)(ws + p.ti);
    float* topw3    = (float*)(ws + p.tw);
    unsigned short* h    = (unsigned short*)(ws + p.h);
    unsigned short* part = (unsigned short*)(ws + p.part);

    // convert expert weights once (12*1024*1024 = 12.58M elems, /2048 per block)
    cvt_bf16<<<6144, 256, 0, stream>>>(W1, W1b);
    cvt_bf16<<<6144, 256, 0, stream>>>(W2, W2b);
    // routing matrix M = U @ Pw (fp64), once
    compute_M<<<36, 256, 0, stream>>>(U1, U2, U3, Pw, Md);

    int gg_tiles = 3 * Nc / 128 + 12;
    for (int c = 0; c < C; ++c) {
        int base = c * Nc;
        zero_counts<<<1, 64, 0, stream>>>(counts1, counts2);
        cvt_bf16<<<Nc / 2, 256, 0, stream>>>(X + (size_t)base * 1024, Xb);
        z_gemm<<<Nc / 128, 256, 0, stream>>>(X, Md, zbuf, base);
        route2<<<Nc / 256, 256, 0, stream>>>(zbuf, counts1, counts2,
                                             bucket1, bucketw1, bucket2, bucketw2,
                                             topi3, topw3, Nc);
        grouped_gemm<<<dim3(gg_tiles, 8), 256, 0, stream>>>(Xb, W1b,
                                                            bucket1, bucketw1, counts1, part, Nc);
        combine_gelu<<<Nc / 2, 256, 0, stream>>>(part, h, Nc);
        grouped_gemm<<<dim3(gg_tiles, 8), 256, 0, stream>>>(h, W2b,
                                                            bucket2, bucketw2, counts2, part, Nc);
        final_out<<<Nc / 2, 256, 0, stream>>>(part, topi3, topw3, B2,
                                              OUT + (size_t)base * 1024, Nc);
    }
}